// Round 1
// baseline (1072.169 us; speedup 1.0000x reference)
//
#include <hip/hip_runtime.h>
#include <stdint.h>

typedef __attribute__((ext_vector_type(4))) float f32x4;
typedef __attribute__((ext_vector_type(2))) float f32x2;
typedef __attribute__((ext_vector_type(8))) short s16x8;
typedef __attribute__((ext_vector_type(4))) unsigned short u16x4;

#define TOKENS 16384
#define IN_F 4096
#define OUT_F 4096
#define RNK 16

static __device__ __forceinline__ unsigned short f32_to_bf16(float f) {
    uint32_t u = __builtin_bit_cast(uint32_t, f);
    uint32_t r = (u + 0x7FFFu + ((u >> 16) & 1u)) >> 16;
    return (unsigned short)r;
}

static __device__ __forceinline__ void direct_load16(const void* g, void* l) {
    __builtin_amdgcn_global_load_lds(
        (const __attribute__((address_space(1))) void*)(uintptr_t)g,
        (__attribute__((address_space(3))) void*)(uintptr_t)l,
        16, 0, 0);
}

// ---------------- Kernel A: per-row absmax int8 quant-dequant -> bf16 ----------------
__global__ __launch_bounds__(256) void qd_weight_kernel(const float* __restrict__ w,
                                                        unsigned short* __restrict__ wbf) {
    const int row = blockIdx.x;
    const int tid = threadIdx.x;
    const float* wr = w + (size_t)row * IN_F;
    f32x4 v[4];
#pragma unroll
    for (int p = 0; p < 4; ++p)
        v[p] = *(const f32x4*)(wr + (size_t)(tid + p * 256) * 4);
    float m = 0.f;
#pragma unroll
    for (int p = 0; p < 4; ++p)
#pragma unroll
        for (int e = 0; e < 4; ++e)
            m = fmaxf(m, fabsf(v[p][e]));
#pragma unroll
    for (int off = 1; off < 64; off <<= 1)
        m = fmaxf(m, __shfl_xor(m, off, 64));
    __shared__ float red[4];
    if ((tid & 63) == 0) red[tid >> 6] = m;
    __syncthreads();
    m = fmaxf(fmaxf(red[0], red[1]), fmaxf(red[2], red[3]));
    const float scale = m * (1.0f / 127.0f);
    const float denom = scale + 1e-8f;
#pragma unroll
    for (int p = 0; p < 4; ++p) {
        u16x4 q4;
#pragma unroll
        for (int e = 0; e < 4; ++e) {
            float q = rintf(v[p][e] / denom);      // RNE, matches jnp.round
            q = fminf(fmaxf(q, -128.f), 127.f);
            q4[e] = f32_to_bf16(q * scale);
        }
        *(u16x4*)(wbf + (size_t)row * IN_F + (size_t)(tid + p * 256) * 4) = q4;
    }
}

// ------------- Kernel B: x f32 -> bf16 conversion fused with t = 2*(x @ lora_a) -------------
// Block = 256 thr (4 waves), 16 tokens/block (4/wave). Lane owns k = j*128 + lane*2 (coalesced).
__global__ __launch_bounds__(256) void conv_lora_kernel(const float* __restrict__ x,
                                                        const float* __restrict__ la,
                                                        unsigned short* __restrict__ xbf,
                                                        float* __restrict__ tsc) {
    const int tid = threadIdx.x;
    const int lane = tid & 63;
    const int wid = tid >> 6;
    const int tok0 = blockIdx.x * 16 + wid * 4;
    float acc[4][16];
#pragma unroll
    for (int ti = 0; ti < 4; ++ti)
#pragma unroll
        for (int r = 0; r < 16; ++r) acc[ti][r] = 0.f;

    for (int j = 0; j < 32; ++j) {
        const int k = j * 128 + lane * 2;
        const float* lap = la + (size_t)k * RNK;
        f32x4 A[4], B[4];
#pragma unroll
        for (int h = 0; h < 4; ++h) A[h] = *(const f32x4*)(lap + h * 4);
#pragma unroll
        for (int h = 0; h < 4; ++h) B[h] = *(const f32x4*)(lap + RNK + h * 4);
#pragma unroll
        for (int ti = 0; ti < 4; ++ti) {
            const int t = tok0 + ti;
            f32x2 xv = *(const f32x2*)(x + (size_t)t * IN_F + k);
            const float xa = xv[0], xb = xv[1];
            uint32_t pack = (uint32_t)f32_to_bf16(xa) | ((uint32_t)f32_to_bf16(xb) << 16);
            *(uint32_t*)(xbf + (size_t)t * IN_F + k) = pack;
#pragma unroll
            for (int h = 0; h < 4; ++h)
#pragma unroll
                for (int e = 0; e < 4; ++e)
                    acc[ti][h * 4 + e] += xa * A[h][e] + xb * B[h][e];
        }
    }
#pragma unroll
    for (int ti = 0; ti < 4; ++ti)
#pragma unroll
        for (int r = 0; r < 16; ++r) {
            float s = acc[ti][r];
#pragma unroll
            for (int off = 1; off < 64; off <<= 1)
                s += __shfl_xor(s, off, 64);
            acc[ti][r] = s;
        }
    if (lane == 0) {
#pragma unroll
        for (int ti = 0; ti < 4; ++ti)
#pragma unroll
            for (int r = 0; r < 16; ++r)
                tsc[(size_t)(tok0 + ti) * RNK + r] = 2.0f * acc[ti][r];
    }
}

// ------------- Kernel C: bf16 MFMA GEMM (out = xbf @ wbf^T) with fused LoRA epilogue -------------
// 128x128 tile, BK=32, 4 waves (2x2), per-wave 64x64 = 4x4 frags of 16x16x32 MFMA.
__global__ __launch_bounds__(256) void gemm_lora_kernel(const unsigned short* __restrict__ xbf,
                                                        const unsigned short* __restrict__ wbf,
                                                        const float* __restrict__ tsc,
                                                        const float* __restrict__ lb,
                                                        float* __restrict__ out) {
    __shared__ unsigned short As[128 * 32];  // 8 KB
    __shared__ unsigned short Bs[128 * 32];  // 8 KB
    const int bid = blockIdx.x;
    // bijective XCD swizzle (nwg = 4096, 4096 % 8 == 0)
    const int swz = (bid & 7) * 512 + (bid >> 3);
    const int tn = swz >> 7;   // 0..31  — consecutive swz share the 1 MB B-panel
    const int tm = swz & 127;  // 0..127
    const int brow = tm * 128;
    const int bcol = tn * 128;
    const int tid = threadIdx.x;
    const int lane = tid & 63;
    const int wid = tid >> 6;
    const int wr = wid >> 1, wc = wid & 1;

    f32x4 acc[4][4];
#pragma unroll
    for (int mm = 0; mm < 4; ++mm)
#pragma unroll
        for (int nn = 0; nn < 4; ++nn)
#pragma unroll
            for (int q = 0; q < 4; ++q) acc[mm][nn][q] = 0.f;

    // staging map: thread covers 8 bf16 at (row = tid/4, col8 = (tid%4)*8); linear LDS matches
    const int srow = tid >> 2;
    const int scol = (tid & 3) * 8;
    const unsigned short* gA = xbf + (size_t)(brow + srow) * IN_F + scol;
    const unsigned short* gB = wbf + (size_t)(bcol + srow) * IN_F + scol;
    char* AsB = (char*)As;
    char* BsB = (char*)Bs;
    const uint32_t ldsoff = (uint32_t)tid * 16u;

    const int lrow = lane & 15;
    const int lk = (lane >> 4) * 8;

    for (int kt = 0; kt < IN_F / 32; ++kt) {
        const int k0 = kt * 32;
        __syncthreads();
        direct_load16(gA + k0, AsB + ldsoff);
        direct_load16(gA + (size_t)64 * IN_F + k0, AsB + 4096 + ldsoff);
        direct_load16(gB + k0, BsB + ldsoff);
        direct_load16(gB + (size_t)64 * IN_F + k0, BsB + 4096 + ldsoff);
        __syncthreads();  // drains vmcnt (global_load_lds) + makes LDS visible
        s16x8 a[4], b[4];
#pragma unroll
        for (int mm = 0; mm < 4; ++mm)
            a[mm] = *(const s16x8*)(As + (wr * 64 + mm * 16 + lrow) * 32 + lk);
#pragma unroll
        for (int nn = 0; nn < 4; ++nn)
            b[nn] = *(const s16x8*)(Bs + (wc * 64 + nn * 16 + lrow) * 32 + lk);
#pragma unroll
        for (int mm = 0; mm < 4; ++mm)
#pragma unroll
            for (int nn = 0; nn < 4; ++nn)
                acc[mm][nn] = __builtin_amdgcn_mfma_f32_16x16x32_bf16(a[mm], b[nn], acc[mm][nn], 0, 0, 0);
    }

    // ---- epilogue: out_tile += t_tile(128x16, prescaled by 2) @ lb_tile(16x128) ----
    __syncthreads();
    float* tls = (float*)As;  // [128 rows][16 r]  (8 KB, reuses As)
    float* lbt = (float*)Bs;  // [128 cols][16 r]  (8 KB, reuses Bs)
    {
        const int row = tid >> 1, r0 = (tid & 1) * 8;
        const float* src = tsc + (size_t)(brow + row) * RNK + r0;
        f32x4 u0 = *(const f32x4*)src;
        f32x4 u1 = *(const f32x4*)(src + 4);
        *(f32x4*)(tls + row * 16 + r0) = u0;
        *(f32x4*)(tls + row * 16 + r0 + 4) = u1;
    }
    {
        const int col = tid & 127, rh = (tid >> 7) * 8;
#pragma unroll
        for (int r2 = 0; r2 < 8; ++r2)
            lbt[col * 16 + rh + r2] = lb[(size_t)(rh + r2) * OUT_F + bcol + col];
    }
    __syncthreads();

    f32x4 lbr[4][4];
#pragma unroll
    for (int nn = 0; nn < 4; ++nn) {
        const int c = wc * 64 + nn * 16 + lrow;
#pragma unroll
        for (int h = 0; h < 4; ++h)
            lbr[nn][h] = *(const f32x4*)(lbt + c * 16 + h * 4);
    }
#pragma unroll
    for (int mm = 0; mm < 4; ++mm) {
#pragma unroll
        for (int q = 0; q < 4; ++q) {
            // C/D layout (verified m89): col = lane&15, row = (lane>>4)*4 + q
            const int rloc = wr * 64 + mm * 16 + (lane >> 4) * 4 + q;
            f32x4 tr[4];
#pragma unroll
            for (int h = 0; h < 4; ++h)
                tr[h] = *(const f32x4*)(tls + rloc * 16 + h * 4);
#pragma unroll
            for (int nn = 0; nn < 4; ++nn) {
                float s = 0.f;
#pragma unroll
                for (int h = 0; h < 4; ++h)
#pragma unroll
                    for (int e = 0; e < 4; ++e)
                        s += tr[h][e] * lbr[nn][h][e];
                const int ocol = bcol + wc * 64 + nn * 16 + lrow;
                out[(size_t)(brow + rloc) * OUT_F + ocol] = acc[mm][nn][q] + s;
            }
        }
    }
}

extern "C" void kernel_launch(void* const* d_in, const int* in_sizes, int n_in,
                              void* d_out, int out_size, void* d_ws, size_t ws_size,
                              hipStream_t stream) {
    const float* x  = (const float*)d_in[0];
    const float* w  = (const float*)d_in[1];
    const float* la = (const float*)d_in[2];
    const float* lb = (const float*)d_in[3];
    float* out = (float*)d_out;

    char* ws = (char*)d_ws;
    unsigned short* xbf = (unsigned short*)ws;                                   // 128 MiB
    unsigned short* wbf = (unsigned short*)(ws + (size_t)TOKENS * IN_F * 2);     // 32 MiB
    float* tsc = (float*)(ws + (size_t)TOKENS * IN_F * 2 + (size_t)OUT_F * IN_F * 2);  // 1 MiB

    qd_weight_kernel<<<OUT_F, 256, 0, stream>>>(w, wbf);
    conv_lora_kernel<<<TOKENS / 16, 256, 0, stream>>>(x, la, xbf, tsc);
    gemm_lora_kernel<<<(TOKENS / 128) * (OUT_F / 128), 256, 0, stream>>>(xbf, wbf, tsc, lb, out);
}

// Round 2
// 750.911 us; speedup vs baseline: 1.4278x; 1.4278x over previous
//
#include <hip/hip_runtime.h>
#include <stdint.h>

typedef __attribute__((ext_vector_type(4))) float f32x4;
typedef __attribute__((ext_vector_type(2))) float f32x2;
typedef __attribute__((ext_vector_type(8))) short s16x8;
typedef __attribute__((ext_vector_type(4))) unsigned short u16x4;

#define TOKENS 16384
#define IN_F 4096
#define OUT_F 4096
#define RNK 16
#define BM 256
#define BN 256
#define BK 64
#define NT (IN_F / BK)

static __device__ __forceinline__ unsigned short f32_to_bf16(float f) {
    uint32_t u = __builtin_bit_cast(uint32_t, f);
    uint32_t r = (u + 0x7FFFu + ((u >> 16) & 1u)) >> 16;
    return (unsigned short)r;
}

static __device__ __forceinline__ void direct_load16(const void* g, void* l) {
    __builtin_amdgcn_global_load_lds(
        (const __attribute__((address_space(1))) void*)(uintptr_t)g,
        (__attribute__((address_space(3))) void*)(uintptr_t)l,
        16, 0, 0);
}

static __device__ __forceinline__ f32x4 mfma16(s16x8 a, s16x8 b, f32x4 c) {
    return __builtin_amdgcn_mfma_f32_16x16x32_bf16(a, b, c, 0, 0, 0);
}

#define RAW_BARRIER() asm volatile("s_barrier" ::: "memory")
#define WAIT_VM0() asm volatile("s_waitcnt vmcnt(0)" ::: "memory")

// ---------------- Kernel A: per-row absmax int8 quant-dequant -> bf16, + lora_b transpose ----------------
__global__ __launch_bounds__(256) void qd_weight_kernel(const float* __restrict__ w,
                                                        const float* __restrict__ lb,
                                                        unsigned short* __restrict__ wbf,
                                                        unsigned short* __restrict__ lbt) {
    const int row = blockIdx.x;
    const int tid = threadIdx.x;
    const float* wr = w + (size_t)row * IN_F;
    f32x4 v[4];
#pragma unroll
    for (int p = 0; p < 4; ++p)
        v[p] = *(const f32x4*)(wr + (size_t)(tid + p * 256) * 4);
    float m = 0.f;
#pragma unroll
    for (int p = 0; p < 4; ++p)
#pragma unroll
        for (int e = 0; e < 4; ++e)
            m = fmaxf(m, fabsf(v[p][e]));
#pragma unroll
    for (int off = 1; off < 64; off <<= 1)
        m = fmaxf(m, __shfl_xor(m, off, 64));
    __shared__ float red[4];
    if ((tid & 63) == 0) red[tid >> 6] = m;
    __syncthreads();
    m = fmaxf(fmaxf(red[0], red[1]), fmaxf(red[2], red[3]));
    const float scale = m * (1.0f / 127.0f);
    const float denom = scale + 1e-8f;
#pragma unroll
    for (int p = 0; p < 4; ++p) {
        u16x4 q4;
#pragma unroll
        for (int e = 0; e < 4; ++e) {
            float q = rintf(v[p][e] / denom);  // RNE, matches jnp.round
            q = fminf(fmaxf(q, -128.f), 127.f);
            q4[e] = f32_to_bf16(q * scale);
        }
        *(u16x4*)(wbf + (size_t)row * IN_F + (size_t)(tid + p * 256) * 4) = q4;
    }
    // lbt[col][r] = bf16(lb[r][col]) ; this block handles col = row
    if (tid < RNK)
        lbt[(size_t)row * RNK + tid] = f32_to_bf16(lb[(size_t)tid * OUT_F + row]);
}

// ------------- Kernel B: x f32 -> bf16 conversion fused with t = bf16(2*(x @ lora_a)) -------------
__global__ __launch_bounds__(256) void conv_lora_kernel(const float* __restrict__ x,
                                                        const float* __restrict__ la,
                                                        unsigned short* __restrict__ xbf,
                                                        unsigned short* __restrict__ tbf) {
    const int tid = threadIdx.x;
    const int lane = tid & 63;
    const int wid = tid >> 6;
    const int tok0 = blockIdx.x * 16 + wid * 4;
    float acc[4][16];
#pragma unroll
    for (int ti = 0; ti < 4; ++ti)
#pragma unroll
        for (int r = 0; r < 16; ++r) acc[ti][r] = 0.f;

    for (int j = 0; j < 32; ++j) {
        const int k = j * 128 + lane * 2;
        const float* lap = la + (size_t)k * RNK;
        f32x4 A[4], B[4];
#pragma unroll
        for (int h = 0; h < 4; ++h) A[h] = *(const f32x4*)(lap + h * 4);
#pragma unroll
        for (int h = 0; h < 4; ++h) B[h] = *(const f32x4*)(lap + RNK + h * 4);
#pragma unroll
        for (int ti = 0; ti < 4; ++ti) {
            const int t = tok0 + ti;
            f32x2 xv = *(const f32x2*)(x + (size_t)t * IN_F + k);
            const float xa = xv[0], xb = xv[1];
            uint32_t pack = (uint32_t)f32_to_bf16(xa) | ((uint32_t)f32_to_bf16(xb) << 16);
            *(uint32_t*)(xbf + (size_t)t * IN_F + k) = pack;
#pragma unroll
            for (int h = 0; h < 4; ++h)
#pragma unroll
                for (int e = 0; e < 4; ++e)
                    acc[ti][h * 4 + e] += xa * A[h][e] + xb * B[h][e];
        }
    }
#pragma unroll
    for (int ti = 0; ti < 4; ++ti)
#pragma unroll
        for (int r = 0; r < 16; ++r) {
            float s = acc[ti][r];
#pragma unroll
            for (int off = 1; off < 64; off <<= 1)
                s += __shfl_xor(s, off, 64);
            acc[ti][r] = s;
        }
    if (lane == 0) {
#pragma unroll
        for (int ti = 0; ti < 4; ++ti)
#pragma unroll
            for (int r = 0; r < 16; ++r)
                tbf[(size_t)(tok0 + ti) * RNK + r] = f32_to_bf16(2.0f * acc[ti][r]);
    }
}

// ------------- Kernel C: 256x256 8-phase bf16 MFMA GEMM (out = xbf @ wbf^T) + MFMA LoRA epilogue -------------
// 512 threads = 8 waves (2M x 4N). BK=64, double-buffered 128KB LDS, XOR-swizzled (both sides).
__global__ __launch_bounds__(512, 2) void gemm8p_kernel(const unsigned short* __restrict__ xbf,
                                                        const unsigned short* __restrict__ wbf,
                                                        const unsigned short* __restrict__ tbf,
                                                        const unsigned short* __restrict__ lbt,
                                                        float* __restrict__ out) {
    __shared__ char lds[131072];  // A0 | A1 | B0 | B1, 32KB each

    const int bid = blockIdx.x;
    // bijective XCD swizzle: 1024 blocks, 1024 % 8 == 0. Each XCD owns 2 full B-panels (4MB = its L2).
    const int swz = (bid & 7) * 128 + (bid >> 3);
    const int tm = swz & 63, tn = swz >> 6;
    const int brow = tm * BM, bcol = tn * BN;

    const int tid = threadIdx.x;
    const int lane = tid & 63;
    const int wid = tid >> 6;
    const int wm = wid >> 2, wn = wid & 3;
    const int lrow = lane & 15;
    const int lko = lane >> 4;

    // ---- staging source (pre-swizzled global col so linear LDS dest == swizzled store) ----
    const int s_r = tid >> 3;                                      // row within 64-row issue block
    const int scb = ((tid & 7) * 16) ^ (((tid >> 3) & 7) << 4);    // swizzled col-byte (0..127)
    const unsigned short* gA = xbf + (size_t)(brow + s_r) * IN_F + (scb >> 1);
    const unsigned short* gB = wbf + (size_t)(bcol + s_r) * IN_F + (scb >> 1);

    // ---- fragment ds_read addressing (swizzled) ----
    const int arow0 = (wm * 128 + lrow) * 128;  // byte base, A buf
    const int brow0 = (wn * 64 + lrow) * 128;   // byte base, B buf
    const int koff[2] = {(lko * 16) ^ ((lrow & 7) << 4),
                         ((lko * 16) | 64) ^ ((lrow & 7) << 4)};

    f32x4 acc[8][4];
#pragma unroll
    for (int mf = 0; mf < 8; ++mf)
#pragma unroll
        for (int nf = 0; nf < 4; ++nf)
#pragma unroll
            for (int q = 0; q < 4; ++q) acc[mf][nf][q] = 0.f;

    // ---- prologue: stage tile 0 into buffer 0 ----
#pragma unroll
    for (int i = 0; i < 4; ++i)
        direct_load16(gA + (size_t)(i * 64) * IN_F, lds + i * 8192 + tid * 16);
#pragma unroll
    for (int i = 0; i < 4; ++i)
        direct_load16(gB + (size_t)(i * 64) * IN_F, lds + 65536 + i * 8192 + tid * 16);
    WAIT_VM0();
    __syncthreads();

    s16x8 a[4][2], bb0[2][2], bb1[2][2];

    for (int t = 0; t < NT; ++t) {
        const int sel = t & 1;
        const char* A = lds + sel * 32768;
        const char* B = lds + 65536 + sel * 32768;
        char* An = lds + (sel ^ 1) * 32768;
        char* Bn = lds + 65536 + (sel ^ 1) * 32768;
        const int k1 = (t + 1) * BK;
        const bool pf = (t + 1 < NT);

        // ===== phase 0: read A-lo + B-lo | stage A(t+1) | MFMA (m0-3 x n0-1) =====
#pragma unroll
        for (int mf = 0; mf < 4; ++mf) {
            a[mf][0] = *(const s16x8*)(A + arow0 + mf * 2048 + koff[0]);
            a[mf][1] = *(const s16x8*)(A + arow0 + mf * 2048 + koff[1]);
        }
#pragma unroll
        for (int nf = 0; nf < 2; ++nf) {
            bb0[nf][0] = *(const s16x8*)(B + brow0 + nf * 2048 + koff[0]);
            bb0[nf][1] = *(const s16x8*)(B + brow0 + nf * 2048 + koff[1]);
        }
        if (pf) {
#pragma unroll
            for (int i = 0; i < 4; ++i)
                direct_load16(gA + (size_t)(i * 64) * IN_F + k1, An + i * 8192 + tid * 16);
        }
        RAW_BARRIER();
        __builtin_amdgcn_s_setprio(1);
#pragma unroll
        for (int mf = 0; mf < 4; ++mf)
#pragma unroll
            for (int nf = 0; nf < 2; ++nf) {
                acc[mf][nf] = mfma16(a[mf][0], bb0[nf][0], acc[mf][nf]);
                acc[mf][nf] = mfma16(a[mf][1], bb0[nf][1], acc[mf][nf]);
            }
        __builtin_amdgcn_s_setprio(0);
        RAW_BARRIER();

        // ===== phase 1: read B-hi | stage B(t+1) | MFMA (m0-3 x n2-3) =====
#pragma unroll
        for (int nf = 0; nf < 2; ++nf) {
            bb1[nf][0] = *(const s16x8*)(B + brow0 + (2 + nf) * 2048 + koff[0]);
            bb1[nf][1] = *(const s16x8*)(B + brow0 + (2 + nf) * 2048 + koff[1]);
        }
        if (pf) {
#pragma unroll
            for (int i = 0; i < 4; ++i)
                direct_load16(gB + (size_t)(i * 64) * IN_F + k1, Bn + i * 8192 + tid * 16);
        }
        RAW_BARRIER();
        __builtin_amdgcn_s_setprio(1);
#pragma unroll
        for (int mf = 0; mf < 4; ++mf)
#pragma unroll
            for (int nf = 0; nf < 2; ++nf) {
                acc[mf][2 + nf] = mfma16(a[mf][0], bb1[nf][0], acc[mf][2 + nf]);
                acc[mf][2 + nf] = mfma16(a[mf][1], bb1[nf][1], acc[mf][2 + nf]);
            }
        __builtin_amdgcn_s_setprio(0);
        RAW_BARRIER();

        // ===== phase 2: read A-hi | MFMA (m4-7 x n2-3) =====
#pragma unroll
        for (int mf = 0; mf < 4; ++mf) {
            a[mf][0] = *(const s16x8*)(A + arow0 + (4 + mf) * 2048 + koff[0]);
            a[mf][1] = *(const s16x8*)(A + arow0 + (4 + mf) * 2048 + koff[1]);
        }
        RAW_BARRIER();
        __builtin_amdgcn_s_setprio(1);
#pragma unroll
        for (int mf = 0; mf < 4; ++mf)
#pragma unroll
            for (int nf = 0; nf < 2; ++nf) {
                acc[4 + mf][2 + nf] = mfma16(a[mf][0], bb1[nf][0], acc[4 + mf][2 + nf]);
                acc[4 + mf][2 + nf] = mfma16(a[mf][1], bb1[nf][1], acc[4 + mf][2 + nf]);
            }
        __builtin_amdgcn_s_setprio(0);
        RAW_BARRIER();

        // ===== phase 3: MFMA (m4-7 x n0-1, bb0 still live) | wait own prefetch | boundary =====
        __builtin_amdgcn_s_setprio(1);
#pragma unroll
        for (int mf = 0; mf < 4; ++mf)
#pragma unroll
            for (int nf = 0; nf < 2; ++nf) {
                acc[4 + mf][nf] = mfma16(a[mf][0], bb0[nf][0], acc[4 + mf][nf]);
                acc[4 + mf][nf] = mfma16(a[mf][1], bb0[nf][1], acc[4 + mf][nf]);
            }
        __builtin_amdgcn_s_setprio(0);
        WAIT_VM0();       // own 8 prefetch loads (issued 3 phases ago) -> cheap
        RAW_BARRIER();    // all waves' loads landed -> next tile's ds_reads safe
    }

    // ---- LoRA epilogue via MFMA: acc += t_tile(256x16) @ lbt_tile(256x16)^T (K=32, k>=16 zero) ----
    __syncthreads();
    unsigned short* tls = (unsigned short*)lds;           // [256][16]
    unsigned short* lls = (unsigned short*)(lds + 8192);  // [256][16]
    {
        const int row = tid >> 1, h = tid & 1;
        *(s16x8*)(tls + row * 16 + h * 8) = *(const s16x8*)(tbf + (size_t)(brow + row) * RNK + h * 8);
        *(s16x8*)(lls + row * 16 + h * 8) = *(const s16x8*)(lbt + (size_t)(bcol + row) * RNK + h * 8);
    }
    __syncthreads();
    {
        s16x8 z;
#pragma unroll
        for (int e = 0; e < 8; ++e) z[e] = 0;
        s16x8 at8[8], bl8[4];
#pragma unroll
        for (int mf = 0; mf < 8; ++mf) {
            const int row = wm * 128 + mf * 16 + lrow;
            at8[mf] = (lko < 2) ? *(const s16x8*)(tls + row * 16 + lko * 8) : z;
        }
#pragma unroll
        for (int nf = 0; nf < 4; ++nf) {
            const int row = wn * 64 + nf * 16 + lrow;
            bl8[nf] = (lko < 2) ? *(const s16x8*)(lls + row * 16 + lko * 8) : z;
        }
#pragma unroll
        for (int mf = 0; mf < 8; ++mf)
#pragma unroll
            for (int nf = 0; nf < 4; ++nf)
                acc[mf][nf] = mfma16(at8[mf], bl8[nf], acc[mf][nf]);
    }

    // ---- store: C/D layout col=lane&15, row=(lane>>4)*4+q (verified) ----
    const int c0 = bcol + wn * 64 + lrow;
    const int r0base = brow + wm * 128 + lko * 4;
#pragma unroll
    for (int mf = 0; mf < 8; ++mf)
#pragma unroll
        for (int q = 0; q < 4; ++q) {
            float* orow = out + (size_t)(r0base + mf * 16 + q) * OUT_F;
#pragma unroll
            for (int nf = 0; nf < 4; ++nf)
                orow[c0 + nf * 16] = acc[mf][nf][q];
        }
}

extern "C" void kernel_launch(void* const* d_in, const int* in_sizes, int n_in,
                              void* d_out, int out_size, void* d_ws, size_t ws_size,
                              hipStream_t stream) {
    const float* x  = (const float*)d_in[0];
    const float* w  = (const float*)d_in[1];
    const float* la = (const float*)d_in[2];
    const float* lb = (const float*)d_in[3];
    float* out = (float*)d_out;

    char* ws = (char*)d_ws;
    unsigned short* xbf = (unsigned short*)ws;                                    // 128 MiB
    unsigned short* wbf = (unsigned short*)(ws + (size_t)TOKENS * IN_F * 2);      // 32 MiB
    unsigned short* tbf = (unsigned short*)(ws + (size_t)TOKENS * IN_F * 2 + (size_t)OUT_F * IN_F * 2);           // 512 KiB
    unsigned short* lbt = (unsigned short*)(ws + (size_t)TOKENS * IN_F * 2 + (size_t)OUT_F * IN_F * 2
                                               + (size_t)TOKENS * RNK * 2);       // 128 KiB

    qd_weight_kernel<<<OUT_F, 256, 0, stream>>>(w, lb, wbf, lbt);
    conv_lora_kernel<<<TOKENS / 16, 256, 0, stream>>>(x, la, xbf, tbf);
    gemm8p_kernel<<<(TOKENS / BM) * (OUT_F / BN), 512, 0, stream>>>(xbf, wbf, tbf, lbt, out);
}

// Round 3
// 743.844 us; speedup vs baseline: 1.4414x; 1.0095x over previous
//
#include <hip/hip_runtime.h>
#include <stdint.h>

typedef __attribute__((ext_vector_type(4))) float f32x4;
typedef __attribute__((ext_vector_type(2))) float f32x2;
typedef __attribute__((ext_vector_type(8))) short s16x8;
typedef __attribute__((ext_vector_type(4))) unsigned short u16x4;

#define TOKENS 16384
#define IN_F 4096
#define OUT_F 4096
#define RNK 16
#define BM 256
#define BN 256
#define BK 64
#define NT (IN_F / BK)

static __device__ __forceinline__ unsigned short f32_to_bf16(float f) {
    uint32_t u = __builtin_bit_cast(uint32_t, f);
    uint32_t r = (u + 0x7FFFu + ((u >> 16) & 1u)) >> 16;
    return (unsigned short)r;
}

static __device__ __forceinline__ void direct_load16(const void* g, void* l) {
    __builtin_amdgcn_global_load_lds(
        (const __attribute__((address_space(1))) void*)(uintptr_t)g,
        (__attribute__((address_space(3))) void*)(uintptr_t)l,
        16, 0, 0);
}

static __device__ __forceinline__ f32x4 mfma16(s16x8 a, s16x8 b, f32x4 c) {
    return __builtin_amdgcn_mfma_f32_16x16x32_bf16(a, b, c, 0, 0, 0);
}

#define RAW_BARRIER() asm volatile("s_barrier" ::: "memory")
#define WAIT_VM0() asm volatile("s_waitcnt vmcnt(0)" ::: "memory")
#define WAIT_VM8() asm volatile("s_waitcnt vmcnt(8)" ::: "memory")

// ---------------- Kernel A: per-row absmax int8 quant-dequant -> bf16, + lora_b transpose ----------------
__global__ __launch_bounds__(256) void qd_weight_kernel(const float* __restrict__ w,
                                                        const float* __restrict__ lb,
                                                        unsigned short* __restrict__ wbf,
                                                        unsigned short* __restrict__ lbt) {
    const int row = blockIdx.x;
    const int tid = threadIdx.x;
    const float* wr = w + (size_t)row * IN_F;
    f32x4 v[4];
#pragma unroll
    for (int p = 0; p < 4; ++p)
        v[p] = *(const f32x4*)(wr + (size_t)(tid + p * 256) * 4);
    float m = 0.f;
#pragma unroll
    for (int p = 0; p < 4; ++p)
#pragma unroll
        for (int e = 0; e < 4; ++e)
            m = fmaxf(m, fabsf(v[p][e]));
#pragma unroll
    for (int off = 1; off < 64; off <<= 1)
        m = fmaxf(m, __shfl_xor(m, off, 64));
    __shared__ float red[4];
    if ((tid & 63) == 0) red[tid >> 6] = m;
    __syncthreads();
    m = fmaxf(fmaxf(red[0], red[1]), fmaxf(red[2], red[3]));
    const float scale = m * (1.0f / 127.0f);
    const float denom = scale + 1e-8f;
#pragma unroll
    for (int p = 0; p < 4; ++p) {
        u16x4 q4;
#pragma unroll
        for (int e = 0; e < 4; ++e) {
            float q = rintf(v[p][e] / denom);  // RNE, matches jnp.round
            q = fminf(fmaxf(q, -128.f), 127.f);
            q4[e] = f32_to_bf16(q * scale);
        }
        *(u16x4*)(wbf + (size_t)row * IN_F + (size_t)(tid + p * 256) * 4) = q4;
    }
    // lbt[col][r] = bf16(lb[r][col]) ; this block handles col = row
    if (tid < RNK)
        lbt[(size_t)row * RNK + tid] = f32_to_bf16(lb[(size_t)tid * OUT_F + row]);
}

// ------------- Kernel B: x f32 -> bf16 conversion fused with t = bf16(2*(x @ lora_a)) -------------
__global__ __launch_bounds__(256) void conv_lora_kernel(const float* __restrict__ x,
                                                        const float* __restrict__ la,
                                                        unsigned short* __restrict__ xbf,
                                                        unsigned short* __restrict__ tbf) {
    const int tid = threadIdx.x;
    const int lane = tid & 63;
    const int wid = tid >> 6;
    const int tok0 = blockIdx.x * 16 + wid * 4;
    float acc[4][16];
#pragma unroll
    for (int ti = 0; ti < 4; ++ti)
#pragma unroll
        for (int r = 0; r < 16; ++r) acc[ti][r] = 0.f;

    for (int j = 0; j < 32; ++j) {
        const int k = j * 128 + lane * 2;
        const float* lap = la + (size_t)k * RNK;
        f32x4 A[4], B[4];
#pragma unroll
        for (int h = 0; h < 4; ++h) A[h] = *(const f32x4*)(lap + h * 4);
#pragma unroll
        for (int h = 0; h < 4; ++h) B[h] = *(const f32x4*)(lap + RNK + h * 4);
#pragma unroll
        for (int ti = 0; ti < 4; ++ti) {
            const int t = tok0 + ti;
            f32x2 xv = *(const f32x2*)(x + (size_t)t * IN_F + k);
            const float xa = xv[0], xb = xv[1];
            uint32_t pack = (uint32_t)f32_to_bf16(xa) | ((uint32_t)f32_to_bf16(xb) << 16);
            *(uint32_t*)(xbf + (size_t)t * IN_F + k) = pack;
#pragma unroll
            for (int h = 0; h < 4; ++h)
#pragma unroll
                for (int e = 0; e < 4; ++e)
                    acc[ti][h * 4 + e] += xa * A[h][e] + xb * B[h][e];
        }
    }
#pragma unroll
    for (int ti = 0; ti < 4; ++ti)
#pragma unroll
        for (int r = 0; r < 16; ++r) {
            float s = acc[ti][r];
#pragma unroll
            for (int off = 1; off < 64; off <<= 1)
                s += __shfl_xor(s, off, 64);
            acc[ti][r] = s;
        }
    if (lane == 0) {
#pragma unroll
        for (int ti = 0; ti < 4; ++ti)
#pragma unroll
            for (int r = 0; r < 16; ++r)
                tbf[(size_t)(tok0 + ti) * RNK + r] = f32_to_bf16(2.0f * acc[ti][r]);
    }
}

// ------------- Kernel C: 256x256 8-phase bf16 MFMA GEMM (out = xbf @ wbf^T) + MFMA LoRA epilogue -------------
// 512 threads = 8 waves (2M x 4N). BK=64, double-buffered 128KB LDS, XOR-swizzled (both sides).
// Pipeline: 2 K-tiles in flight; counted boundary wait vmcnt(8) (T4), never 0 in steady state.
__global__ __launch_bounds__(512, 2) void gemm8p_kernel(const unsigned short* __restrict__ xbf,
                                                        const unsigned short* __restrict__ wbf,
                                                        const unsigned short* __restrict__ tbf,
                                                        const unsigned short* __restrict__ lbt,
                                                        float* __restrict__ out) {
    __shared__ char lds[131072];  // A0 | A1 | B0 | B1, 32KB each

    const int bid = blockIdx.x;
    // bijective XCD swizzle: 1024 blocks, 1024 % 8 == 0. Each XCD owns 2 full B-panels (4MB = its L2).
    const int swz = (bid & 7) * 128 + (bid >> 3);
    const int tm = swz & 63, tn = swz >> 6;
    const int brow = tm * BM, bcol = tn * BN;

    const int tid = threadIdx.x;
    const int lane = tid & 63;
    const int wid = tid >> 6;
    const int wm = wid >> 2, wn = wid & 3;
    const int lrow = lane & 15;
    const int lko = lane >> 4;

    // ---- staging source (pre-swizzled global col so linear LDS dest == swizzled store) ----
    const int s_r = tid >> 3;                                    // row within 64-row issue block
    const int scb = ((tid & 7) * 16) ^ (((tid >> 3) & 7) << 4);  // swizzled col-byte (0..127)
    const unsigned short* gA = xbf + (size_t)(brow + s_r) * IN_F + (scb >> 1);
    const unsigned short* gB = wbf + (size_t)(bcol + s_r) * IN_F + (scb >> 1);

    // ---- fragment ds_read addressing (swizzled) ----
    const int arow0 = (wm * 128 + lrow) * 128;  // byte base, A buf
    const int brow0 = (wn * 64 + lrow) * 128;   // byte base, B buf
    const int koff[2] = {(lko * 16) ^ ((lrow & 7) << 4),
                         ((lko * 16) | 64) ^ ((lrow & 7) << 4)};

    f32x4 acc[8][4];
#pragma unroll
    for (int mf = 0; mf < 8; ++mf)
#pragma unroll
        for (int nf = 0; nf < 4; ++nf)
#pragma unroll
            for (int q = 0; q < 4; ++q) acc[mf][nf][q] = 0.f;

    // ---- prologue: stage tile 0 (buf0) and tile 1 (buf1). Issue order: A0,B0,B1,A1 ----
#pragma unroll
    for (int i = 0; i < 4; ++i)
        direct_load16(gA + (size_t)(i * 64) * IN_F, lds + i * 8192 + tid * 16);
#pragma unroll
    for (int i = 0; i < 4; ++i)
        direct_load16(gB + (size_t)(i * 64) * IN_F, lds + 65536 + i * 8192 + tid * 16);
#pragma unroll
    for (int i = 0; i < 4; ++i)
        direct_load16(gB + (size_t)(i * 64) * IN_F + BK, lds + 65536 + 32768 + i * 8192 + tid * 16);
#pragma unroll
    for (int i = 0; i < 4; ++i)
        direct_load16(gA + (size_t)(i * 64) * IN_F + BK, lds + 32768 + i * 8192 + tid * 16);
    WAIT_VM8();  // tile 0 landed; tile 1's 8 loads stay in flight
    __syncthreads();

    s16x8 a[4][2], bb0[2][2], bb1[2][2];

    for (int t = 0; t < NT; ++t) {
        const int sel = t & 1;
        const char* A = lds + sel * 32768;
        const char* B = lds + 65536 + sel * 32768;
        char* An = lds + sel * 32768;           // A(t+2) goes to same-parity buffer
        char* Bn = lds + 65536 + sel * 32768;
        const int k2 = (t + 2) * BK;
        const bool pf = (t + 2 < NT);

        // ===== phase 0: ds_read A(t) m0-3 + B(t) n0-1 | MFMA (m0-3 x n0-1) =====
#pragma unroll
        for (int mf = 0; mf < 4; ++mf) {
            a[mf][0] = *(const s16x8*)(A + arow0 + mf * 2048 + koff[0]);
            a[mf][1] = *(const s16x8*)(A + arow0 + mf * 2048 + koff[1]);
        }
#pragma unroll
        for (int nf = 0; nf < 2; ++nf) {
            bb0[nf][0] = *(const s16x8*)(B + brow0 + nf * 2048 + koff[0]);
            bb0[nf][1] = *(const s16x8*)(B + brow0 + nf * 2048 + koff[1]);
        }
        RAW_BARRIER();
        __builtin_amdgcn_s_setprio(1);
#pragma unroll
        for (int mf = 0; mf < 4; ++mf)
#pragma unroll
            for (int nf = 0; nf < 2; ++nf) {
                acc[mf][nf] = mfma16(a[mf][0], bb0[nf][0], acc[mf][nf]);
                acc[mf][nf] = mfma16(a[mf][1], bb0[nf][1], acc[mf][nf]);
            }
        __builtin_amdgcn_s_setprio(0);
        RAW_BARRIER();

        // ===== phase 1: ds_read B(t) n2-3 | MFMA (m0-3 x n2-3) =====
#pragma unroll
        for (int nf = 0; nf < 2; ++nf) {
            bb1[nf][0] = *(const s16x8*)(B + brow0 + (2 + nf) * 2048 + koff[0]);
            bb1[nf][1] = *(const s16x8*)(B + brow0 + (2 + nf) * 2048 + koff[1]);
        }
        RAW_BARRIER();
        __builtin_amdgcn_s_setprio(1);
#pragma unroll
        for (int mf = 0; mf < 4; ++mf)
#pragma unroll
            for (int nf = 0; nf < 2; ++nf) {
                acc[mf][2 + nf] = mfma16(a[mf][0], bb1[nf][0], acc[mf][2 + nf]);
                acc[mf][2 + nf] = mfma16(a[mf][1], bb1[nf][1], acc[mf][2 + nf]);
            }
        __builtin_amdgcn_s_setprio(0);
        RAW_BARRIER();

        // ===== phase 2: issue B(t+2) | ds_read A(t) m4-7 | MFMA (m4-7 x n2-3) =====
        // B(t)'s last reads were phase 1 (pre-barrier) -> safe to overwrite-in-flight now.
        if (pf) {
#pragma unroll
            for (int i = 0; i < 4; ++i)
                direct_load16(gB + (size_t)(i * 64) * IN_F + k2, Bn + i * 8192 + tid * 16);
        }
#pragma unroll
        for (int mf = 0; mf < 4; ++mf) {
            a[mf][0] = *(const s16x8*)(A + arow0 + (4 + mf) * 2048 + koff[0]);
            a[mf][1] = *(const s16x8*)(A + arow0 + (4 + mf) * 2048 + koff[1]);
        }
        RAW_BARRIER();
        __builtin_amdgcn_s_setprio(1);
#pragma unroll
        for (int mf = 0; mf < 4; ++mf)
#pragma unroll
            for (int nf = 0; nf < 2; ++nf) {
                acc[4 + mf][2 + nf] = mfma16(a[mf][0], bb1[nf][0], acc[4 + mf][2 + nf]);
                acc[4 + mf][2 + nf] = mfma16(a[mf][1], bb1[nf][1], acc[4 + mf][2 + nf]);
            }
        __builtin_amdgcn_s_setprio(0);
        RAW_BARRIER();

        // ===== phase 3: issue A(t+2) | MFMA (m4-7 x n0-1) | counted boundary wait =====
        // A(t)'s last reads were phase 2 (pre-barrier) -> safe now.
        if (pf) {
#pragma unroll
            for (int i = 0; i < 4; ++i)
                direct_load16(gA + (size_t)(i * 64) * IN_F + k2, An + i * 8192 + tid * 16);
        }
        __builtin_amdgcn_s_setprio(1);
#pragma unroll
        for (int mf = 0; mf < 4; ++mf)
#pragma unroll
            for (int nf = 0; nf < 2; ++nf) {
                acc[4 + mf][nf] = mfma16(a[mf][0], bb0[nf][0], acc[4 + mf][nf]);
                acc[4 + mf][nf] = mfma16(a[mf][1], bb0[nf][1], acc[4 + mf][nf]);
            }
        __builtin_amdgcn_s_setprio(0);
        // vmcnt in-order retirement: ==8 left means tile t+1's 8 oldest loads landed;
        // tile t+2's 8 stay in flight across the barrier (T4: never drain to 0).
        if (pf) { WAIT_VM8(); } else { WAIT_VM0(); }
        RAW_BARRIER();
    }

    // ---- LoRA epilogue via MFMA: acc += t_tile(256x16) @ lbt_tile(256x16)^T (K=32, k>=16 zero) ----
    __syncthreads();
    unsigned short* tls = (unsigned short*)lds;           // [256][16]
    unsigned short* lls = (unsigned short*)(lds + 8192);  // [256][16]
    {
        const int row = tid >> 1, h = tid & 1;
        *(s16x8*)(tls + row * 16 + h * 8) = *(const s16x8*)(tbf + (size_t)(brow + row) * RNK + h * 8);
        *(s16x8*)(lls + row * 16 + h * 8) = *(const s16x8*)(lbt + (size_t)(bcol + row) * RNK + h * 8);
    }
    __syncthreads();
    {
        s16x8 z;
#pragma unroll
        for (int e = 0; e < 8; ++e) z[e] = 0;
        s16x8 at8[8], bl8[4];
#pragma unroll
        for (int mf = 0; mf < 8; ++mf) {
            const int row = wm * 128 + mf * 16 + lrow;
            at8[mf] = (lko < 2) ? *(const s16x8*)(tls + row * 16 + lko * 8) : z;
        }
#pragma unroll
        for (int nf = 0; nf < 4; ++nf) {
            const int row = wn * 64 + nf * 16 + lrow;
            bl8[nf] = (lko < 2) ? *(const s16x8*)(lls + row * 16 + lko * 8) : z;
        }
#pragma unroll
        for (int mf = 0; mf < 8; ++mf)
#pragma unroll
            for (int nf = 0; nf < 4; ++nf)
                acc[mf][nf] = mfma16(at8[mf], bl8[nf], acc[mf][nf]);
    }

    // ---- store: C/D layout col=lane&15, row=(lane>>4)*4+q (verified) ----
    const int c0 = bcol + wn * 64 + lrow;
    const int r0base = brow + wm * 128 + lko * 4;
#pragma unroll
    for (int mf = 0; mf < 8; ++mf)
#pragma unroll
        for (int q = 0; q < 4; ++q) {
            float* orow = out + (size_t)(r0base + mf * 16 + q) * OUT_F;
#pragma unroll
            for (int nf = 0; nf < 4; ++nf)
                orow[c0 + nf * 16] = acc[mf][nf][q];
        }
}

extern "C" void kernel_launch(void* const* d_in, const int* in_sizes, int n_in,
                              void* d_out, int out_size, void* d_ws, size_t ws_size,
                              hipStream_t stream) {
    const float* x  = (const float*)d_in[0];
    const float* w  = (const float*)d_in[1];
    const float* la = (const float*)d_in[2];
    const float* lb = (const float*)d_in[3];
    float* out = (float*)d_out;

    char* ws = (char*)d_ws;
    unsigned short* xbf = (unsigned short*)ws;                                    // 128 MiB
    unsigned short* wbf = (unsigned short*)(ws + (size_t)TOKENS * IN_F * 2);      // 32 MiB
    unsigned short* tbf = (unsigned short*)(ws + (size_t)TOKENS * IN_F * 2 + (size_t)OUT_F * IN_F * 2);           // 512 KiB
    unsigned short* lbt = (unsigned short*)(ws + (size_t)TOKENS * IN_F * 2 + (size_t)OUT_F * IN_F * 2
                                               + (size_t)TOKENS * RNK * 2);       // 128 KiB

    qd_weight_kernel<<<OUT_F, 256, 0, stream>>>(w, lb, wbf, lbt);
    conv_lora_kernel<<<TOKENS / 16, 256, 0, stream>>>(x, la, xbf, tbf);
    gemm8p_kernel<<<(TOKENS / BM) * (OUT_F / BN), 512, 0, stream>>>(xbf, wbf, tbf, lbt, out);
}